// Round 1
// baseline (127.624 us; speedup 1.0000x reference)
//
#include <hip/hip_runtime.h>

#define SDIM 65536
#define NCIRC 64
#define PI_F 3.14159265358979323846f
#define INV_SQRT2 0.70710678118654752440f

__device__ __forceinline__ float2 cmul(float2 a, float2 b) {
    return make_float2(a.x*b.x - a.y*b.y, a.x*b.y + a.y*b.x);
}

// RY butterfly on a register-bit qubit: pairs (j, j|BIT) within the 32 amps.
template<int BIT>
__device__ __forceinline__ void reg_gate(float* re, float* im, float c, float s) {
#pragma unroll
    for (int j = 0; j < 32; ++j) {
        if (!(j & BIT)) {
            const int k = j | BIT;
            float r0 = re[j], r1 = re[k];
            re[j] = c*r0 - s*r1;
            re[k] = s*r0 + c*r1;
            float i0 = im[j], i1 = im[k];
            im[j] = c*i0 - s*i1;
            im[k] = s*i0 + c*i1;
        }
    }
}

// RY butterfly on a lane-bit qubit (bits 0..5 of tid): cross-lane shuffle.
__device__ __forceinline__ void lane_gate(float* re, float* im, int tid, int qbit,
                                          float c, float s) {
    const int mask = 1 << qbit;
    const float sg = (tid & mask) ? s : -s;
#pragma unroll
    for (int j = 0; j < 32; ++j) {
        float pr = __shfl_xor(re[j], mask, 64);
        float pi = __shfl_xor(im[j], mask, 64);
        re[j] = c*re[j] + sg*pr;
        im[j] = c*im[j] + sg*pi;
    }
}

// One component of a wave-bit qubit gate: exchange via LDS (float4, pad 9 slots).
__device__ __forceinline__ void wave_exchange_apply(float* v, int tid, int mask,
                                                    float c, float sg, float4* ex) {
    float4* mine = ex + tid * 9;
#pragma unroll
    for (int j4 = 0; j4 < 8; ++j4)
        mine[j4] = make_float4(v[4*j4+0], v[4*j4+1], v[4*j4+2], v[4*j4+3]);
    __syncthreads();
    const float4* po = ex + (tid ^ mask) * 9;
#pragma unroll
    for (int j4 = 0; j4 < 8; ++j4) {
        float4 t = po[j4];
        v[4*j4+0] = c*v[4*j4+0] + sg*t.x;
        v[4*j4+1] = c*v[4*j4+1] + sg*t.y;
        v[4*j4+2] = c*v[4*j4+2] + sg*t.z;
        v[4*j4+3] = c*v[4*j4+3] + sg*t.w;
    }
    __syncthreads();
}

__device__ __forceinline__ void wave_gate(float* re, float* im, int tid, int qbit,
                                          float c, float s, float4* ex) {
    const int mask = 1 << qbit;
    const float sg = (tid & mask) ? s : -s;
    wave_exchange_apply(re, tid, mask, c, sg, ex);
    wave_exchange_apply(im, tid, mask, c, sg, ex);
}

// ---------------- K1: init product state + phi0 (CRZ layer 0, shift 1) + RY(alpha) q0..12
// chunk = state bits 13..15; local idx = (j<<8)|tid ; j bits -> state bits 8..12
__global__ __launch_bounds__(256, 2)
void k1_init(const float* __restrict__ x, const float* __restrict__ wcrz,
             const float* __restrict__ wry, const float* __restrict__ scale_p,
             float2* __restrict__ st) {
    const int tid = threadIdx.x;
    const int n = blockIdx.x >> 3;
    const int c = blockIdx.x & 7;

    __shared__ float2 TL[256], TH[256], C0[16];
    __shared__ float gc[16], gs[16];          // alpha = wry0 + enc, half-angle cos/sin
    __shared__ float v0s[16], v1s[16], t0s[16];
    __shared__ float4 ex[256 * 9];

    if (tid < 16) {
        const int q = tid;
        const int b = n >> 3, p = n & 7;
        const int h = q >> 2, w = q & 3;
        const float xv = x[b*128 + h*32 + p*4 + w];
        const float enc = tanhf(xv * scale_p[0]) * PI_F;
        float sE, cE;
        sincosf(0.5f * enc, &sE, &cE);
        v0s[q] = (cE - sE) * INV_SQRT2;      // RY(enc)*H |0>
        v1s[q] = (cE + sE) * INV_SQRT2;
        sincosf(0.5f * (wry[q] + enc), &gs[q], &gc[q]);   // merged RY(w0)+RY(enc)
        t0s[q] = 0.5f * wcrz[q];             // layer-0 CRZ half angles
    }
    __syncthreads();

    // build per-WG tables: TL/TH = product state halves * e^{i A/B}, C0 = cross phase
    {
        float prod = 1.f, ang = 0.f;
#pragma unroll
        for (int q = 0; q < 8; ++q) prod *= ((tid >> q) & 1) ? v1s[q] : v0s[q];
#pragma unroll
        for (int q = 0; q < 7; ++q)
            if ((tid >> q) & 1) ang += ((tid >> (q + 1)) & 1) ? t0s[q] : -t0s[q];
        float sa, ca;
        sincosf(ang, &sa, &ca);
        TL[tid] = make_float2(prod * ca, prod * sa);

        prod = 1.f; ang = 0.f;
#pragma unroll
        for (int q = 0; q < 8; ++q) prod *= ((tid >> q) & 1) ? v1s[q + 8] : v0s[q + 8];
#pragma unroll
        for (int q = 0; q < 7; ++q)
            if ((tid >> q) & 1) ang += ((tid >> (q + 1)) & 1) ? t0s[q + 8] : -t0s[q + 8];
        sincosf(ang, &sa, &ca);
        TH[tid] = make_float2(prod * ca, prod * sa);

        if (tid < 16) {   // cross bits: b0, b7, b8, b15  (gates q=7 and q=15)
            const int b0 = tid & 1, b7 = (tid >> 1) & 1, b8 = (tid >> 2) & 1, b15 = (tid >> 3) & 1;
            float a2 = 0.f;
            if (b7)  a2 += b8 ? t0s[7]  : -t0s[7];
            if (b15) a2 += b0 ? t0s[15] : -t0s[15];
            float s2, c2;
            sincosf(a2, &s2, &c2);
            C0[tid] = make_float2(c2, s2);
        }
    }
    __syncthreads();

    float re[32], im[32];
    {
        const int b0 = tid & 1, b7 = (tid >> 7) & 1, b15 = (c >> 2) & 1;
        float2 pre[2];
#pragma unroll
        for (int b8 = 0; b8 < 2; ++b8) {
            const int ci = b0 | (b7 << 1) | (b8 << 2) | (b15 << 3);
            pre[b8] = cmul(TL[tid], C0[ci]);
        }
#pragma unroll
        for (int j = 0; j < 32; ++j) {
            float2 a = cmul(pre[j & 1], TH[(c << 5) | j]);
            re[j] = a.x; im[j] = a.y;
        }
    }

    // RY(alpha) on local qubits 0..12
    reg_gate<1 >(re, im, gc[8],  gs[8]);
    reg_gate<2 >(re, im, gc[9],  gs[9]);
    reg_gate<4 >(re, im, gc[10], gs[10]);
    reg_gate<8 >(re, im, gc[11], gs[11]);
    reg_gate<16>(re, im, gc[12], gs[12]);
#pragma unroll
    for (int q = 0; q < 6; ++q) lane_gate(re, im, tid, q, gc[q], gs[q]);
    wave_gate(re, im, tid, 6, gc[6], gs[6], ex);
    wave_gate(re, im, tid, 7, gc[7], gs[7], ex);

    float2* outp = st + (size_t)n * SDIM + (c << 13) + tid;
#pragma unroll
    for (int j = 0; j < 32; ++j)
        outp[j << 8] = make_float2(re[j], im[j]);
}

// ---------------- K2: RY(alpha) q13..15 + phi1 (CRZ layer 1, shift 2) + RY(beta) q not in {10,11,12}
// chunk = state bits 10..12; j bits -> state bits {8,9,13,14,15}
__global__ __launch_bounds__(256, 2)
void k2_mid(const float* __restrict__ x, const float* __restrict__ wcrz,
            const float* __restrict__ wry, const float* __restrict__ scale_p,
            float2* __restrict__ st) {
    const int tid = threadIdx.x;
    const int n = blockIdx.x >> 3;
    const int c = blockIdx.x & 7;

    __shared__ float2 A1[256], B1[256], C1[256];
    __shared__ float ac[3], as_[3];           // alpha for qubits 13..15
    __shared__ float bc[16], bs[16];          // beta = wry1
    __shared__ float t1s[16];
    __shared__ float4 ex[256 * 9];

    if (tid < 16) {
        const int q = tid;
        const int b = n >> 3, p = n & 7;
        const int h = q >> 2, w = q & 3;
        const float enc = tanhf(x[b*128 + h*32 + p*4 + w] * scale_p[0]) * PI_F;
        if (q >= 13) sincosf(0.5f * (wry[q] + enc), &as_[q - 13], &ac[q - 13]);
        sincosf(0.5f * wry[16 + q], &bs[q], &bc[q]);
        t1s[q] = 0.5f * wcrz[16 + q];
    }
    __syncthreads();

    // phi1 tables: A1(lo): gates q=0..5 (tgt q+2); B1(hi): q=8..13; C1: cross q=6,7,14,15
    {
        float ang = 0.f;
#pragma unroll
        for (int q = 0; q < 6; ++q)
            if ((tid >> q) & 1) ang += ((tid >> (q + 2)) & 1) ? t1s[q] : -t1s[q];
        float s, cc;
        sincosf(ang, &s, &cc);
        A1[tid] = make_float2(cc, s);

        ang = 0.f;
#pragma unroll
        for (int q = 0; q < 6; ++q)
            if ((tid >> q) & 1) ang += ((tid >> (q + 2)) & 1) ? t1s[q + 8] : -t1s[q + 8];
        sincosf(ang, &s, &cc);
        B1[tid] = make_float2(cc, s);

        // C1 index bits: b0,b1,b6,b7,b8,b9,b14,b15 at positions 0..7
        const int b0 = tid & 1, b1 = (tid >> 1) & 1, b6 = (tid >> 2) & 1, b7 = (tid >> 3) & 1,
                  b8 = (tid >> 4) & 1, b9 = (tid >> 5) & 1, b14 = (tid >> 6) & 1, b15 = (tid >> 7) & 1;
        ang = 0.f;
        if (b6)  ang += b8 ? t1s[6]  : -t1s[6];
        if (b7)  ang += b9 ? t1s[7]  : -t1s[7];
        if (b14) ang += b0 ? t1s[14] : -t1s[14];
        if (b15) ang += b1 ? t1s[15] : -t1s[15];
        sincosf(ang, &s, &cc);
        C1[tid] = make_float2(cc, s);
    }
    __syncthreads();

    float re[32], im[32];
    const float2* base = st + (size_t)n * SDIM + (c << 10) + tid;
#pragma unroll
    for (int j = 0; j < 32; ++j) {
        const int off = ((j & 3) << 8) + ((j >> 2) << 13);
        float2 a = base[off];
        re[j] = a.x; im[j] = a.y;
    }

    // finish RY(alpha): qubits 13,14,15 = j bits 2,3,4
    reg_gate<4 >(re, im, ac[0], as_[0]);
    reg_gate<8 >(re, im, ac[1], as_[1]);
    reg_gate<16>(re, im, ac[2], as_[2]);

    // phi1 pointwise
    {
        const float2 pa = A1[tid];
        const int tl = (tid & 3) | (((tid >> 6) & 3) << 2);
#pragma unroll
        for (int j = 0; j < 32; ++j) {
            const int hi = (j & 3) | (c << 2) | ((j >> 2) << 5);
            const int ci = tl | ((j & 3) << 4) | ((j >> 3) << 6);
            const float2 ph = cmul(cmul(pa, B1[hi]), C1[ci]);
            const float r = re[j], q2 = im[j];
            re[j] = r * ph.x - q2 * ph.y;
            im[j] = r * ph.y + q2 * ph.x;
        }
    }

    // RY(beta) on local qubits: reg {8,9,13,14,15}, lane 0..5, wave 6,7
    reg_gate<1 >(re, im, bc[8],  bs[8]);
    reg_gate<2 >(re, im, bc[9],  bs[9]);
    reg_gate<4 >(re, im, bc[13], bs[13]);
    reg_gate<8 >(re, im, bc[14], bs[14]);
    reg_gate<16>(re, im, bc[15], bs[15]);
#pragma unroll
    for (int q = 0; q < 6; ++q) lane_gate(re, im, tid, q, bc[q], bs[q]);
    wave_gate(re, im, tid, 6, bc[6], bs[6], ex);
    wave_gate(re, im, tid, 7, bc[7], bs[7], ex);

    float2* ob = st + (size_t)n * SDIM + (c << 10) + tid;
#pragma unroll
    for (int j = 0; j < 32; ++j) {
        const int off = ((j & 3) << 8) + ((j >> 2) << 13);
        ob[off] = make_float2(re[j], im[j]);
    }
}

// ---------------- K3: RY(beta) q10..12 + measure -> per-WG partial z[16]
// chunk = state bits 13..15 (same mapping as K1)
__global__ __launch_bounds__(256, 2)
void k3_measure(const float* __restrict__ wry, const float2* __restrict__ st,
                float* __restrict__ partial) {
    const int tid = threadIdx.x;
    const int n = blockIdx.x >> 3;
    const int c = blockIdx.x & 7;

    float bс10s, bc10, b11s, b11c, b12s, b12c;
    sincosf(0.5f * wry[16 + 10], &bс10s, &bc10);
    sincosf(0.5f * wry[16 + 11], &b11s, &b11c);
    sincosf(0.5f * wry[16 + 12], &b12s, &b12c);

    float re[32], im[32];
    const float2* base = st + (size_t)n * SDIM + (c << 13) + tid;
#pragma unroll
    for (int j = 0; j < 32; ++j) {
        float2 a = base[j << 8];
        re[j] = a.x; im[j] = a.y;
    }

    reg_gate<4 >(re, im, bc10, bс10s);
    reg_gate<8 >(re, im, b11c, b11s);
    reg_gate<16>(re, im, b12c, b12s);

    // probs and per-thread partial sums
    float P = 0.f, T0 = 0.f, T1 = 0.f, T2 = 0.f, T3 = 0.f, T4 = 0.f;
#pragma unroll
    for (int j = 0; j < 32; ++j) {
        const float p = re[j]*re[j] + im[j]*im[j];
        P += p;
        if (j & 1)  T0 += p;
        if (j & 2)  T1 += p;
        if (j & 4)  T2 += p;
        if (j & 8)  T3 += p;
        if (j & 16) T4 += p;
    }

    float z[16];
#pragma unroll
    for (int q = 0; q < 8; ++q) z[q] = ((tid >> q) & 1) ? -P : P;
    z[8]  = P - 2.f * T0;
    z[9]  = P - 2.f * T1;
    z[10] = P - 2.f * T2;
    z[11] = P - 2.f * T3;
    z[12] = P - 2.f * T4;
#pragma unroll
    for (int q = 13; q < 16; ++q) z[q] = ((c >> (q - 13)) & 1) ? -P : P;

    // wave reduce (64 lanes)
#pragma unroll
    for (int off = 1; off < 64; off <<= 1) {
#pragma unroll
        for (int q = 0; q < 16; ++q) z[q] += __shfl_xor(z[q], off, 64);
    }

    __shared__ float wz[4][16];
    const int wave = tid >> 6, lane = tid & 63;
    if (lane == 0) {
#pragma unroll
        for (int q = 0; q < 16; ++q) wz[wave][q] = z[q];
    }
    __syncthreads();
    if (tid < 16)
        partial[(size_t)blockIdx.x * 16 + tid] =
            wz[0][tid] + wz[1][tid] + wz[2][tid] + wz[3][tid];
}

// ---------------- K4: reduce 8 chunks, clip, scatter to output layout
__global__ void k4_out(const float* __restrict__ partial, float* __restrict__ out) {
    const int o = blockIdx.x * 256 + threadIdx.x;   // 1024 outputs
    const int b = o >> 7, r = o & 127;
    const int h = r >> 5, r2 = r & 31, p = r2 >> 2, w = r2 & 3;
    const int n = b * 8 + p, q = h * 4 + w;
    float s = 0.f;
#pragma unroll
    for (int cc = 0; cc < 8; ++cc) s += partial[(size_t)(n * 8 + cc) * 16 + q];
    out[o] = fminf(1.f, fmaxf(-1.f, s));
}

extern "C" void kernel_launch(void* const* d_in, const int* in_sizes, int n_in,
                              void* d_out, int out_size, void* d_ws, size_t ws_size,
                              hipStream_t stream) {
    const float* x     = (const float*)d_in[0];
    const float* wcrz  = (const float*)d_in[1];
    const float* wry   = (const float*)d_in[2];
    const float* scale = (const float*)d_in[3];
    float2* st      = (float2*)d_ws;
    float* partial  = (float*)((char*)d_ws + (size_t)NCIRC * SDIM * sizeof(float2));
    float* out      = (float*)d_out;

    k1_init<<<512, 256, 0, stream>>>(x, wcrz, wry, scale, st);
    k2_mid <<<512, 256, 0, stream>>>(x, wcrz, wry, scale, st);
    k3_measure<<<512, 256, 0, stream>>>(wry, st, partial);
    k4_out<<<4, 256, 0, stream>>>(partial, out);
}